// Round 17
// baseline (517.120 us; speedup 1.0000x reference)
//
#include <hip/hip_runtime.h>
#include <math.h>

#define B_   64
#define T_   200
#define DM   256
#define DI   512
#define NH   16
#define HD   32
#define DSZ  16
#define CD   544
#define DIP  1072
#define M_TOT (B_*T_)   // 12800
#define NCH_ 129
#define KENC 192
#define NCHUNK 10
#define CLEN  20

typedef unsigned short u16;
typedef unsigned int u32;
typedef _Float16 f16;
typedef __attribute__((ext_vector_type(8))) _Float16 half8;
typedef __attribute__((ext_vector_type(4))) short short4v;
typedef __attribute__((ext_vector_type(4))) float f32x4;

// ---------------- helpers ----------------------------------------------------
__device__ __forceinline__ float wave_sum(float v) {
    #pragma unroll
    for (int off = 32; off > 0; off >>= 1) v += __shfl_xor(v, off);
    return v;
}
__device__ __forceinline__ u16 f16bits(float a) {
    f16 h = (f16)a;
    return __builtin_bit_cast(u16, h);
}
__device__ __forceinline__ float f16tof(u16 v) {
    return (float)__builtin_bit_cast(f16, v);
}

// ---------------- emb mean over channels ------------------------------------
__global__ void emb_mean_k(const float* __restrict__ emb, float* __restrict__ em) {
    int d = threadIdx.x;
    float s = 0.f;
    for (int c = 0; c < NCH_; ++c) s += emb[c * DM + d];
    em[d] = s * (1.f / NCH_);
}

// ---------------- encoder dwconv (K=3) -> A2 single-f16 [M x KENC] ----------
__global__ void xsA2_k(const float* __restrict__ x, const float* __restrict__ w,
                       const float* __restrict__ b, u16* __restrict__ A2) {
    int idx = blockIdx.x * blockDim.x + threadIdx.x;
    if (idx >= M_TOT * KENC) return;
    int c = idx % KENC;
    int m = idx / KENC;
    float acc = 0.f;
    if (c < NCH_) {
        int t = m % T_;
        int bb = m / T_;
        const float* xr = x + (size_t)(bb * NCH_ + c) * T_;
        acc = b[c];
        if (t > 0)      acc += w[c*3+0] * xr[t-1];
        acc += w[c*3+1] * xr[t];
        if (t < T_-1)   acc += w[c*3+2] * xr[t+1];
    }
    A2[(size_t)m * KENC + c] = f16bits(acc);
}

// ---------------- pack weights fp32 -> f16 single ---------------------------
__global__ void pack_b2s_k(const float* __restrict__ W, u16* __restrict__ B2,
                           int L, int N, int Npad, int Kreal, int K) {
    int idx = blockIdx.x * blockDim.x + threadIdx.x;
    if (idx >= L * Npad * K) return;
    int k = idx % K;
    int n = (idx / K) % Npad;
    int l = idx / (K * Npad);
    u16 hi = 0;
    if (n < N && k < Kreal)
        hi = f16bits(W[((size_t)l * N + n) * Kreal + k]);
    B2[((size_t)l * Npad + n) * K + k] = hi;
}

// ---------------- MFMA f16 GEMM: 64x128 tile, f16 output (in_proj) ----------
__global__ __launch_bounds__(256) void gemm_m64n128h(const u16* __restrict__ A2,
                                                     const u16* __restrict__ B2,
                                                     u16* __restrict__ C,
                                                     int K2, int ldc, int Nreal,
                                                     int nbx) {
    __shared__ u16 As[64 * 64];
    __shared__ u16 Bs[128 * 64];
    int nwg = gridDim.x;
    int lin = blockIdx.x;
    int q = nwg >> 3, r = nwg & 7;
    int xcd = lin & 7, idx = lin >> 3;
    int wg = ((xcd < r) ? xcd * (q + 1) : r * (q + 1) + (xcd - r) * q) + idx;
    int bx = wg % nbx, by = wg / nbx;

    int tid = threadIdx.x;
    int lane = tid & 63;
    int wave = tid >> 6;
    int wr = wave >> 1;
    int wc = wave & 1;
    int bm = by * 64;
    int bn = bx * 128;

    f32x4 acc[2][4] = {};
    const size_t ldA = (size_t)K2 * 2;

    for (int k0 = 0; k0 < K2; k0 += 64) {
        #pragma unroll
        for (int c = 0; c < 2; ++c) {
            int o = c * 4096 + tid * 16;
            int row = o >> 7;
            int slot = (o >> 4) & 7;
            int ss = slot ^ (row & 7);
            const char* src = (const char*)A2 + (size_t)(bm + row) * ldA
                              + (size_t)k0 * 2 + ss * 16;
            __builtin_amdgcn_global_load_lds(
                (const __attribute__((address_space(1))) u32*)src,
                (__attribute__((address_space(3))) u32*)((char*)As + o),
                16, 0, 0);
        }
        #pragma unroll
        for (int c = 0; c < 4; ++c) {
            int o = c * 4096 + tid * 16;
            int row = o >> 7;
            int slot = (o >> 4) & 7;
            int ss = slot ^ (row & 7);
            const char* src = (const char*)B2 + (size_t)(bn + row) * ldA
                              + (size_t)k0 * 2 + ss * 16;
            __builtin_amdgcn_global_load_lds(
                (const __attribute__((address_space(1))) u32*)src,
                (__attribute__((address_space(3))) u32*)((char*)Bs + o),
                16, 0, 0);
        }
        __syncthreads();
        #pragma unroll
        for (int kk = 0; kk < 2; ++kk) {
            int lslot = kk * 4 + (lane >> 4);
            half8 afr[2], bfr[4];
            #pragma unroll
            for (int n = 0; n < 4; ++n) {
                int row = wc * 64 + n * 16 + (lane & 15);
                int ps = lslot ^ (row & 7);
                bfr[n] = *(const half8*)((const char*)Bs + row * 128 + ps * 16);
            }
            #pragma unroll
            for (int m = 0; m < 2; ++m) {
                int row = wr * 32 + m * 16 + (lane & 15);
                int ps = lslot ^ (row & 7);
                afr[m] = *(const half8*)((const char*)As + row * 128 + ps * 16);
            }
            #pragma unroll
            for (int m = 0; m < 2; ++m)
                #pragma unroll
                for (int n = 0; n < 4; ++n)
                    acc[m][n] = __builtin_amdgcn_mfma_f32_16x16x32_f16(
                        bfr[n], afr[m], acc[m][n], 0, 0, 0);
        }
        __syncthreads();
    }

    int crow0 = bm + wr * 32;
    int ccol0 = bn + wc * 64;
    #pragma unroll
    for (int m = 0; m < 2; ++m) {
        int row = crow0 + m * 16 + (lane & 15);
        #pragma unroll
        for (int n = 0; n < 4; ++n) {
            int col = ccol0 + n * 16 + (lane >> 4) * 4;
            if (col < Nreal) {
                short4v hv;
                #pragma unroll
                for (int j = 0; j < 4; ++j) hv[j] = (short)f16bits(acc[m][n][j]);
                *(short4v*)(C + (size_t)row * ldc + col) = hv;
            }
        }
    }
}

// ---------------- MFMA f16 GEMM: 64x64 tile, f32 out (encoder) --------------
__global__ __launch_bounds__(256) void gemm_m64n64(const u16* __restrict__ A2,
                                                   const u16* __restrict__ B2,
                                                   float* __restrict__ C,
                                                   int K2, int ldc, int Nreal,
                                                   int nbx) {
    __shared__ u16 As[64 * 64];
    __shared__ u16 Bs[64 * 64];
    int nwg = gridDim.x;
    int lin = blockIdx.x;
    int q = nwg >> 3, r = nwg & 7;
    int xcd = lin & 7, idx = lin >> 3;
    int wg = ((xcd < r) ? xcd * (q + 1) : r * (q + 1) + (xcd - r) * q) + idx;
    int bx = wg % nbx, by = wg / nbx;

    int tid = threadIdx.x;
    int lane = tid & 63;
    int wave = tid >> 6;
    int wr = wave >> 1;
    int wc = wave & 1;
    int bm = by * 64;
    int bn = bx * 64;

    f32x4 acc[2][2] = {};
    const size_t ldA = (size_t)K2 * 2;

    for (int k0 = 0; k0 < K2; k0 += 64) {
        #pragma unroll
        for (int c = 0; c < 2; ++c) {
            int o = c * 4096 + tid * 16;
            int row = o >> 7;
            int slot = (o >> 4) & 7;
            int ss = slot ^ (row & 7);
            const char* src = (const char*)A2 + (size_t)(bm + row) * ldA
                              + (size_t)k0 * 2 + ss * 16;
            __builtin_amdgcn_global_load_lds(
                (const __attribute__((address_space(1))) u32*)src,
                (__attribute__((address_space(3))) u32*)((char*)As + o),
                16, 0, 0);
        }
        #pragma unroll
        for (int c = 0; c < 2; ++c) {
            int o = c * 4096 + tid * 16;
            int row = o >> 7;
            int slot = (o >> 4) & 7;
            int ss = slot ^ (row & 7);
            const char* src = (const char*)B2 + (size_t)(bn + row) * ldA
                              + (size_t)k0 * 2 + ss * 16;
            __builtin_amdgcn_global_load_lds(
                (const __attribute__((address_space(1))) u32*)src,
                (__attribute__((address_space(3))) u32*)((char*)Bs + o),
                16, 0, 0);
        }
        __syncthreads();
        #pragma unroll
        for (int kk = 0; kk < 2; ++kk) {
            int lslot = kk * 4 + (lane >> 4);
            half8 afr[2], bfr[2];
            #pragma unroll
            for (int n = 0; n < 2; ++n) {
                int row = wc * 32 + n * 16 + (lane & 15);
                int ps = lslot ^ (row & 7);
                bfr[n] = *(const half8*)((const char*)Bs + row * 128 + ps * 16);
            }
            #pragma unroll
            for (int m = 0; m < 2; ++m) {
                int row = wr * 32 + m * 16 + (lane & 15);
                int ps = lslot ^ (row & 7);
                afr[m] = *(const half8*)((const char*)As + row * 128 + ps * 16);
            }
            #pragma unroll
            for (int m = 0; m < 2; ++m)
                #pragma unroll
                for (int n = 0; n < 2; ++n)
                    acc[m][n] = __builtin_amdgcn_mfma_f32_16x16x32_f16(
                        bfr[n], afr[m], acc[m][n], 0, 0, 0);
        }
        __syncthreads();
    }

    int crow0 = bm + wr * 32;
    int ccol0 = bn + wc * 32;
    #pragma unroll
    for (int m = 0; m < 2; ++m) {
        int row = crow0 + m * 16 + (lane & 15);
        #pragma unroll
        for (int n = 0; n < 2; ++n) {
            int col = ccol0 + n * 16 + (lane >> 4) * 4;
            if (col < Nreal)
                *(f32x4*)(C + (size_t)row * ldc + col) = acc[m][n];
        }
    }
}

// ---------------- MFMA f16 GEMM: 64x64 tile, f16 out (out_proj) -------------
__global__ __launch_bounds__(256) void gemm_m64n64h(const u16* __restrict__ A2,
                                                    const u16* __restrict__ B2,
                                                    u16* __restrict__ C,
                                                    int K2, int ldc, int Nreal,
                                                    int nbx) {
    __shared__ u16 As[64 * 64];
    __shared__ u16 Bs[64 * 64];
    int nwg = gridDim.x;
    int lin = blockIdx.x;
    int q = nwg >> 3, r = nwg & 7;
    int xcd = lin & 7, idx = lin >> 3;
    int wg = ((xcd < r) ? xcd * (q + 1) : r * (q + 1) + (xcd - r) * q) + idx;
    int bx = wg % nbx, by = wg / nbx;

    int tid = threadIdx.x;
    int lane = tid & 63;
    int wave = tid >> 6;
    int wr = wave >> 1;
    int wc = wave & 1;
    int bm = by * 64;
    int bn = bx * 64;

    f32x4 acc[2][2] = {};
    const size_t ldA = (size_t)K2 * 2;

    for (int k0 = 0; k0 < K2; k0 += 64) {
        #pragma unroll
        for (int c = 0; c < 2; ++c) {
            int o = c * 4096 + tid * 16;
            int row = o >> 7;
            int slot = (o >> 4) & 7;
            int ss = slot ^ (row & 7);
            const char* src = (const char*)A2 + (size_t)(bm + row) * ldA
                              + (size_t)k0 * 2 + ss * 16;
            __builtin_amdgcn_global_load_lds(
                (const __attribute__((address_space(1))) u32*)src,
                (__attribute__((address_space(3))) u32*)((char*)As + o),
                16, 0, 0);
        }
        #pragma unroll
        for (int c = 0; c < 2; ++c) {
            int o = c * 4096 + tid * 16;
            int row = o >> 7;
            int slot = (o >> 4) & 7;
            int ss = slot ^ (row & 7);
            const char* src = (const char*)B2 + (size_t)(bn + row) * ldA
                              + (size_t)k0 * 2 + ss * 16;
            __builtin_amdgcn_global_load_lds(
                (const __attribute__((address_space(1))) u32*)src,
                (__attribute__((address_space(3))) u32*)((char*)Bs + o),
                16, 0, 0);
        }
        __syncthreads();
        #pragma unroll
        for (int kk = 0; kk < 2; ++kk) {
            int lslot = kk * 4 + (lane >> 4);
            half8 afr[2], bfr[2];
            #pragma unroll
            for (int n = 0; n < 2; ++n) {
                int row = wc * 32 + n * 16 + (lane & 15);
                int ps = lslot ^ (row & 7);
                bfr[n] = *(const half8*)((const char*)Bs + row * 128 + ps * 16);
            }
            #pragma unroll
            for (int m = 0; m < 2; ++m) {
                int row = wr * 32 + m * 16 + (lane & 15);
                int ps = lslot ^ (row & 7);
                afr[m] = *(const half8*)((const char*)As + row * 128 + ps * 16);
            }
            #pragma unroll
            for (int m = 0; m < 2; ++m)
                #pragma unroll
                for (int n = 0; n < 2; ++n)
                    acc[m][n] = __builtin_amdgcn_mfma_f32_16x16x32_f16(
                        bfr[n], afr[m], acc[m][n], 0, 0, 0);
        }
        __syncthreads();
    }

    int crow0 = bm + wr * 32;
    int ccol0 = bn + wc * 32;
    #pragma unroll
    for (int m = 0; m < 2; ++m) {
        int row = crow0 + m * 16 + (lane & 15);
        #pragma unroll
        for (int n = 0; n < 2; ++n) {
            int col = ccol0 + n * 16 + (lane >> 4) * 4;
            if (col < Nreal) {
                short4v hv;
                #pragma unroll
                for (int j = 0; j < 4; ++j) hv[j] = (short)f16bits(acc[m][n][j]);
                *(short4v*)(C + (size_t)row * ldc + col) = hv;
            }
        }
    }
}

// ---------------- encoder LN: h += mb+em; LN; write h + A2 (single, K=256) --
__global__ __launch_bounds__(256) void enc_ln_k(float* __restrict__ h,
        const float* __restrict__ mb, const float* __restrict__ em,
        const float* __restrict__ w, const float* __restrict__ bb,
        u16* __restrict__ A2) {
    int row = blockIdx.x * 4 + (threadIdx.x >> 6);
    int lane = threadIdx.x & 63;
    int e = lane * 4;
    float* hr = h + (size_t)row * DM;
    f32x4 v = *(const f32x4*)(hr + e);
    f32x4 vm = *(const f32x4*)(mb + e);
    f32x4 ve = *(const f32x4*)(em + e);
    float s = 0.f, sq = 0.f;
    #pragma unroll
    for (int j = 0; j < 4; ++j) {
        v[j] += vm[j] + ve[j];
        s += v[j];
        sq += v[j] * v[j];
    }
    s = wave_sum(s); sq = wave_sum(sq);
    float mean = s * (1.f / DM);
    float var = sq * (1.f / DM) - mean * mean;
    float r = rsqrtf(var + 1e-5f);
    f32x4 vw = *(const f32x4*)(w + e);
    f32x4 vb = *(const f32x4*)(bb + e);
    f32x4 o;
    short4v hi4;
    #pragma unroll
    for (int j = 0; j < 4; ++j) {
        float ov = (v[j] - mean) * r * vw[j] + vb[j];
        o[j] = ov;
        hi4[j] = (short)f16bits(ov);
    }
    *(f32x4*)(hr + e) = o;
    *(short4v*)(A2 + (size_t)row * 256 + e) = hi4;
}

// ---------------- scan pass 1: B/C+dt in LDS, x-conv in regs ----------------
__global__ __launch_bounds__(128) void scan1_k(const u16* __restrict__ zx,
        const float* __restrict__ cw, const float* __restrict__ cb,
        const float* __restrict__ dtb_in, const float* __restrict__ A_log,
        const float* __restrict__ D_skip,
        float* __restrict__ y, float* __restrict__ S, float* __restrict__ Pprod) {
    __shared__ float zbc[CLEN + 3][32];
    __shared__ float BCs[CLEN][32];
    __shared__ float dtA[CLEN][4][2];
    int c   = blockIdx.x % NCHUNK;
    int bhq = blockIdx.x / NCHUNK;
    int b   = bhq >> 2;
    int hq  = bhq & 3;
    int tid = threadIdx.x;
    int hl  = tid >> 5;
    int h   = hq * 4 + hl;
    int p   = tid & 31;
    int ch  = h * HD + p;
    int t0  = c * CLEN;
    int base = b * T_ + t0;

    // cooperative: raw B/C z-window into LDS
    for (int i = tid; i < (CLEN + 3) * 32; i += 128) {
        int tt = i >> 5, cc = i & 31;
        int tg = t0 + tt - 3;
        zbc[tt][cc] = (tg >= 0)
            ? f16tof(zx[(size_t)(b * T_ + tg) * DIP + DI + 512 + cc]) : 0.f;
    }
    // cooperative: dt/dA
    for (int i = tid; i < CLEN * 4; i += 128) {
        int t = i >> 2, hh = hq * 4 + (i & 3);
        float xv = f16tof(zx[(size_t)(base + t) * DIP + DI + CD + hh]) + dtb_in[hh];
        float dtv = (xv > 20.f) ? xv : log1pf(expf(xv));
        dtA[t][i & 3][0] = dtv;
        dtA[t][i & 3][1] = expf(dtv * (-expf(A_log[hh])));
    }
    __syncthreads();
    // cooperative: conv+silu on B/C
    for (int i = tid; i < CLEN * 32; i += 128) {
        int t = i >> 5, cc = i & 31;
        int c2 = 512 + cc;
        float acc = cb[c2] + cw[c2*4+0] * zbc[t][cc] + cw[c2*4+1] * zbc[t+1][cc]
                  + cw[c2*4+2] * zbc[t+2][cc] + cw[c2*4+3] * zbc[t+3][cc];
        BCs[t][cc] = acc / (1.f + expf(-acc));
    }
    __syncthreads();

    float Dh = D_skip[h];
    float w0 = cw[ch*4+0], w1 = cw[ch*4+1], w2 = cw[ch*4+2], w3 = cw[ch*4+3];
    float cbb = cb[ch];
    float s[16];
    #pragma unroll
    for (int n = 0; n < 16; ++n) s[n] = 0.f;
    float pr = 1.f;
    const u16* xsrc = zx + (size_t)base * DIP + DI + ch;
    float xm3 = (t0 >= 3) ? f16tof(xsrc[-3 * (ptrdiff_t)DIP]) : 0.f;
    float xm2 = (t0 >= 2) ? f16tof(xsrc[-2 * (ptrdiff_t)DIP]) : 0.f;
    float xm1 = (t0 >= 1) ? f16tof(xsrc[-1 * (ptrdiff_t)DIP]) : 0.f;
    float x0  = f16tof(xsrc[0]);
    for (int t = 0; t < CLEN; ++t) {
        int m = base + t;
        int tn = (t + 1 < CLEN) ? t + 1 : t;
        float x0n = f16tof(xsrc[(size_t)tn * DIP]);
        float dt = dtA[t][hl][0];
        float dA = dtA[t][hl][1];
        float a = cbb + w0 * xm3 + w1 * xm2 + w2 * xm1 + w3 * x0;
        float xh = a / (1.f + expf(-a));
        pr *= dA;
        float dtx = dt * xh;
        float ya0 = 0.f, ya1 = 0.f, ya2 = 0.f, ya3 = 0.f;
        #pragma unroll
        for (int qq = 0; qq < 4; ++qq) {
            f32x4 Bv = *(const f32x4*)&BCs[t][qq * 4];
            f32x4 Cv = *(const f32x4*)&BCs[t][16 + qq * 4];
            #pragma unroll
            for (int j = 0; j < 4; ++j) {
                int n = qq * 4 + j;
                s[n] = fmaf(dA, s[n], dtx * Bv[j]);
                float prod = s[n] * Cv[j];
                if (qq == 0) ya0 += prod;
                else if (qq == 1) ya1 += prod;
                else if (qq == 2) ya2 += prod;
                else ya3 += prod;
            }
        }
        y[(size_t)m * DI + ch] = fmaf(Dh, xh, (ya0 + ya1) + (ya2 + ya3));
        xm3 = xm2; xm2 = xm1; xm1 = x0; x0 = x0n;
    }
    size_t sidx = ((((size_t)b * NH + h) * NCHUNK + c) * 32 + p) * 16;
    #pragma unroll
    for (int qq = 0; qq < 4; ++qq) {
        f32x4 v; v[0]=s[qq*4]; v[1]=s[qq*4+1]; v[2]=s[qq*4+2]; v[3]=s[qq*4+3];
        *(f32x4*)(S + sidx + qq * 4) = v;
    }
    if (p == 0) Pprod[(b * NH + h) * NCHUNK + c] = pr;
}

// ---------------- scan pass 3: C+dA in LDS; y += cum*(C.si) -----------------
__global__ __launch_bounds__(128) void scan3_k(const u16* __restrict__ zx,
        const float* __restrict__ cw, const float* __restrict__ cb,
        const float* __restrict__ dtb_in, const float* __restrict__ A_log,
        const float* __restrict__ S, const float* __restrict__ Pprod,
        float* __restrict__ y) {
    __shared__ float zc[CLEN + 3][16];
    __shared__ float Cs[CLEN][16];
    __shared__ float dAs[CLEN][4];
    int c   = (blockIdx.x % (NCHUNK - 1)) + 1;
    int bhq = blockIdx.x / (NCHUNK - 1);
    int b   = bhq >> 2;
    int hq  = bhq & 3;
    int tid = threadIdx.x;
    int hl  = tid >> 5;
    int h   = hq * 4 + hl;
    int p   = tid & 31;
    int t0  = c * CLEN;
    int base = b * T_ + t0;
    size_t bh = (size_t)b * NH + h;

    for (int i = tid; i < (CLEN + 3) * 16; i += 128) {
        int tt = i >> 4, cc = i & 15;
        int tg = t0 + tt - 3;
        zc[tt][cc] = (tg >= 0)
            ? f16tof(zx[(size_t)(b * T_ + tg) * DIP + DI + 528 + cc]) : 0.f;
    }
    for (int i = tid; i < CLEN * 4; i += 128) {
        int t = i >> 2, hh = hq * 4 + (i & 3);
        float xv = f16tof(zx[(size_t)(base + t) * DIP + DI + CD + hh]) + dtb_in[hh];
        float dtv = (xv > 20.f) ? xv : log1pf(expf(xv));
        dAs[t][i & 3] = expf(dtv * (-expf(A_log[hh])));
    }
    __syncthreads();
    for (int i = tid; i < CLEN * 16; i += 128) {
        int t = i >> 4, cc = i & 15;
        int c2 = 528 + cc;
        float acc = cb[c2] + cw[c2*4+0] * zc[t][cc] + cw[c2*4+1] * zc[t+1][cc]
                  + cw[c2*4+2] * zc[t+2][cc] + cw[c2*4+3] * zc[t+3][cc];
        Cs[t][cc] = acc / (1.f + expf(-acc));
    }
    __syncthreads();

    float si[16];
    #pragma unroll
    for (int n = 0; n < 16; ++n) si[n] = 0.f;
    float wgt = 1.f;
    for (int j = c - 1; j >= 0; --j) {
        size_t eidx = ((bh * NCHUNK + j) * 32 + p) * 16;
        #pragma unroll
        for (int qq = 0; qq < 4; ++qq) {
            f32x4 e = *(const f32x4*)(S + eidx + qq * 4);
            #pragma unroll
            for (int jj = 0; jj < 4; ++jj)
                si[qq*4+jj] = fmaf(wgt, e[jj], si[qq*4+jj]);
        }
        wgt *= Pprod[bh * NCHUNK + j];
    }
    float cum = 1.f;
    for (int t = 0; t < CLEN; ++t) {
        int m = base + t;
        cum *= dAs[t][hl];
        float dot = 0.f;
        #pragma unroll
        for (int qq = 0; qq < 4; ++qq) {
            f32x4 Cv = *(const f32x4*)&Cs[t][qq * 4];
            #pragma unroll
            for (int jj = 0; jj < 4; ++jj) dot = fmaf(si[qq*4+jj], Cv[jj], dot);
        }
        y[(size_t)m * DI + h * HD + p] += cum * dot;
    }
}

// ---------------- gated RMSNorm -> A2 single-f16 (z from f16 zx) ------------
__global__ __launch_bounds__(256) void gate_rms_k(const float* __restrict__ y,
        const u16* __restrict__ zx, const float* __restrict__ nw,
        u16* __restrict__ A2) {
    int row = blockIdx.x * 4 + (threadIdx.x >> 6);
    int lane = threadIdx.x & 63;
    int e0 = lane * 4, e1 = 256 + lane * 4;
    const float* yr = y + (size_t)row * DI;
    const u16* zr = zx + (size_t)row * DIP;
    f32x4 y0 = *(const f32x4*)(yr + e0);
    f32x4 y1 = *(const f32x4*)(yr + e1);
    short4v zh0 = *(const short4v*)(zr + e0);
    short4v zh1 = *(const short4v*)(zr + e1);
    f32x4 g0, g1;
    float sq = 0.f;
    #pragma unroll
    for (int j = 0; j < 4; ++j) {
        float z0 = f16tof((u16)zh0[j]);
        float z1 = f16tof((u16)zh1[j]);
        g0[j] = y0[j] * (z0 / (1.f + expf(-z0)));
        g1[j] = y1[j] * (z1 / (1.f + expf(-z1)));
        sq += g0[j] * g0[j] + g1[j] * g1[j];
    }
    sq = wave_sum(sq);
    float r = rsqrtf(sq * (1.f / DI) + 1e-5f);
    f32x4 w0 = *(const f32x4*)(nw + e0);
    f32x4 w1 = *(const f32x4*)(nw + e1);
    u16* ar = A2 + (size_t)row * 512;
    short4v hi4;
    #pragma unroll
    for (int j = 0; j < 4; ++j)
        hi4[j] = (short)f16bits(g0[j] * r * w0[j]);
    *(short4v*)(ar + e0) = hi4;
    #pragma unroll
    for (int j = 0; j < 4; ++j)
        hi4[j] = (short)f16bits(g1[j] * r * w1[j]);
    *(short4v*)(ar + e1) = hi4;
}

// ---------------- h = LN(c + h), c in f16 -> h + A2 (single, K=256) ---------
__global__ __launch_bounds__(256) void add_ln_k(float* __restrict__ h,
        const u16* __restrict__ c, const float* __restrict__ w,
        const float* __restrict__ bb, u16* __restrict__ A2) {
    int row = blockIdx.x * 4 + (threadIdx.x >> 6);
    int lane = threadIdx.x & 63;
    int e = lane * 4;
    float* hr = h + (size_t)row * DM;
    const u16* cr = c + (size_t)row * DM;
    f32x4 v = *(const f32x4*)(hr + e);
    short4v ch4 = *(const short4v*)(cr + e);
    float s = 0.f, sq = 0.f;
    #pragma unroll
    for (int j = 0; j < 4; ++j) {
        v[j] += f16tof((u16)ch4[j]);
        s += v[j];
        sq += v[j] * v[j];
    }
    s = wave_sum(s); sq = wave_sum(sq);
    float mean = s * (1.f / DM);
    float var = sq * (1.f / DM) - mean * mean;
    float r = rsqrtf(var + 1e-5f);
    f32x4 vw = *(const f32x4*)(w + e);
    f32x4 vb = *(const f32x4*)(bb + e);
    f32x4 o;
    short4v hi4;
    #pragma unroll
    for (int j = 0; j < 4; ++j) {
        float ov = (v[j] - mean) * r * vw[j] + vb[j];
        o[j] = ov;
        hi4[j] = (short)f16bits(ov);
    }
    *(f32x4*)(hr + e) = o;
    *(short4v*)(A2 + (size_t)row * 256 + e) = hi4;
}

// ---------------- fused mean-pool + head ------------------------------------
__global__ __launch_bounds__(256) void pool_head_k(const float* __restrict__ h,
        const float* __restrict__ w1, const float* __restrict__ b1,
        const float* __restrict__ w2, const float* __restrict__ b2,
        float* __restrict__ out) {
    __shared__ float pl[DM];
    __shared__ float red[2];
    int b = blockIdx.x, tid = threadIdx.x;
    float s = 0.f;
    for (int t = 0; t < T_; ++t) s += h[(size_t)(b * T_ + t) * DM + tid];
    pl[tid] = s * (1.f / T_);
    __syncthreads();
    float v = 0.f;
    if (tid < 128) {
        float acc = b1[tid];
        #pragma unroll 4
        for (int d = 0; d < DM; ++d) acc = fmaf(pl[d], w1[tid * DM + d], acc);
        v = fmaxf(acc, 0.f) * w2[tid];
    }
    #pragma unroll
    for (int off = 32; off > 0; off >>= 1) v += __shfl_xor(v, off);
    if (tid == 0) red[0] = v;
    if (tid == 64) red[1] = v;
    __syncthreads();
    if (tid == 0) out[b] = red[0] + red[1] + b2[0];
}

extern "C" void kernel_launch(void* const* d_in, const int* in_sizes, int n_in,
                              void* d_out, int out_size, void* d_ws, size_t ws_size,
                              hipStream_t stream) {
    const float* x         = (const float*)d_in[0];
    const float* emb       = (const float*)d_in[1];
    const float* sconv_w   = (const float*)d_in[2];
    const float* sconv_b   = (const float*)d_in[3];
    const float* mixer_w   = (const float*)d_in[4];
    const float* mixer_b   = (const float*)d_in[5];
    const float* enc_ln_w  = (const float*)d_in[6];
    const float* enc_ln_b  = (const float*)d_in[7];
    const float* in_proj_w = (const float*)d_in[8];
    const float* conv_w    = (const float*)d_in[9];
    const float* conv_b    = (const float*)d_in[10];
    const float* dt_bias   = (const float*)d_in[11];
    const float* A_log     = (const float*)d_in[12];
    const float* D_skip    = (const float*)d_in[13];
    const float* norm_w    = (const float*)d_in[14];
    const float* out_proj_w= (const float*)d_in[15];
    const float* ln_w      = (const float*)d_in[16];
    const float* ln_b      = (const float*)d_in[17];
    const float* head1_w   = (const float*)d_in[18];
    const float* head1_b   = (const float*)d_in[19];
    const float* head2_w   = (const float*)d_in[20];
    const float* head2_b   = (const float*)d_in[21];
    float* out = (float*)d_out;

    float* ws  = (float*)d_ws;
    float* h    = ws;                          // M*DM f32
    float* y    = h  + (size_t)M_TOT * DM;     // M*DI f32
    float* em   = y  + (size_t)M_TOT * DI;     // 256
    float* S    = em + 256;                    // B*NH*NCHUNK*512 f32
    float* Pprod = S + (size_t)B_*NH*NCHUNK*512;  // 10240
    u16* zx   = (u16*)(Pprod + 10240);         // M*DIP f16
    u16* cbuf = zx + (size_t)M_TOT * DIP;      // M*DM f16
    u16* A2   = cbuf + (size_t)M_TOT * DM;     // M*512 f16 (max: out_proj K=512)
    u16* B2e  = A2 + (size_t)M_TOT * 512;      // 256*192
    u16* B2i  = B2e + (size_t)256 * 192;       // 4*1152*256
    u16* B2o  = B2i + (size_t)4 * 1152 * 256;  // 4*256*512

    // ---- one-time packs ----
    emb_mean_k<<<1, DM, 0, stream>>>(emb, em);
    pack_b2s_k<<<(256 * KENC + 255) / 256, 256, 0, stream>>>(
        mixer_w, B2e, 1, DM, DM, NCH_, KENC);
    pack_b2s_k<<<(4 * 1152 * DM + 255) / 256, 256, 0, stream>>>(
        in_proj_w, B2i, 4, DIP, 1152, DM, DM);
    pack_b2s_k<<<(4 * 256 * DI + 255) / 256, 256, 0, stream>>>(
        out_proj_w, B2o, 4, DM, DM, DI, DI);

    // ---- encoder ----
    xsA2_k<<<(M_TOT * KENC + 255) / 256, 256, 0, stream>>>(x, sconv_w, sconv_b, A2);
    gemm_m64n64<<<4 * 200, 256, 0, stream>>>(A2, B2e, h, KENC, DM, DM, 4);
    enc_ln_k<<<M_TOT / 4, 256, 0, stream>>>(h, mixer_b, em, enc_ln_w, enc_ln_b, A2);

    for (int l = 0; l < 4; ++l) {
        // in_proj: single-f16, K2=256, N=1072 (pad 1152), f16 output
        gemm_m64n128h<<<9 * 200, 256, 0, stream>>>(
            A2, B2i + (size_t)l * 1152 * 256, zx, 256, DIP, DIP, 9);

        scan1_k<<<B_ * 4 * NCHUNK, 128, 0, stream>>>(
            zx, conv_w + l * CD * 4, conv_b + l * CD, dt_bias + l * NH,
            A_log + l * NH, D_skip + l * NH, y, S, Pprod);
        scan3_k<<<B_ * 4 * (NCHUNK - 1), 128, 0, stream>>>(
            zx, conv_w + l * CD * 4, conv_b + l * CD, dt_bias + l * NH,
            A_log + l * NH, S, Pprod, y);

        gate_rms_k<<<M_TOT / 4, 256, 0, stream>>>(y, zx, norm_w + l * DI, A2);

        // out_proj: single-f16, K2=512, N=256, f16 output
        gemm_m64n64h<<<4 * 200, 256, 0, stream>>>(
            A2, B2o + (size_t)l * 256 * 512, cbuf, 512, DM, DM, 4);

        add_ln_k<<<M_TOT / 4, 256, 0, stream>>>(h, cbuf, ln_w + l * DM, ln_b + l * DM, A2);
    }

    pool_head_k<<<B_, 256, 0, stream>>>(h, head1_w, head1_b, head2_w, head2_b, out);
}

// Round 18
// 483.312 us; speedup vs baseline: 1.0700x; 1.0700x over previous
//
#include <hip/hip_runtime.h>
#include <math.h>

#define B_   64
#define T_   200
#define DM   256
#define DI   512
#define NH   16
#define HD   32
#define DSZ  16
#define CD   544
#define DIP  1072
#define M_TOT (B_*T_)   // 12800
#define NCH_ 129
#define KENC 192
#define NCHUNK 10
#define CLEN  20
#define NBC  48         // compact B|C row: B[0..15] C[16..31]

typedef unsigned short u16;
typedef unsigned int u32;
typedef _Float16 f16;
typedef __attribute__((ext_vector_type(8))) _Float16 half8;
typedef __attribute__((ext_vector_type(4))) short short4v;
typedef __attribute__((ext_vector_type(4))) float f32x4;
typedef __attribute__((ext_vector_type(2))) float f32x2;

// ---------------- helpers ----------------------------------------------------
__device__ __forceinline__ float wave_sum(float v) {
    #pragma unroll
    for (int off = 32; off > 0; off >>= 1) v += __shfl_xor(v, off);
    return v;
}
__device__ __forceinline__ u16 f16bits(float a) {
    f16 h = (f16)a;
    return __builtin_bit_cast(u16, h);
}
__device__ __forceinline__ float f16tof(u16 v) {
    return (float)__builtin_bit_cast(f16, v);
}

// ---------------- emb mean over channels ------------------------------------
__global__ void emb_mean_k(const float* __restrict__ emb, float* __restrict__ em) {
    int d = threadIdx.x;
    float s = 0.f;
    for (int c = 0; c < NCH_; ++c) s += emb[c * DM + d];
    em[d] = s * (1.f / NCH_);
}

// ---------------- encoder dwconv (K=3) -> A2 single-f16 [M x KENC] ----------
__global__ void xsA2_k(const float* __restrict__ x, const float* __restrict__ w,
                       const float* __restrict__ b, u16* __restrict__ A2) {
    int idx = blockIdx.x * blockDim.x + threadIdx.x;
    if (idx >= M_TOT * KENC) return;
    int c = idx % KENC;
    int m = idx / KENC;
    float acc = 0.f;
    if (c < NCH_) {
        int t = m % T_;
        int bb = m / T_;
        const float* xr = x + (size_t)(bb * NCH_ + c) * T_;
        acc = b[c];
        if (t > 0)      acc += w[c*3+0] * xr[t-1];
        acc += w[c*3+1] * xr[t];
        if (t < T_-1)   acc += w[c*3+2] * xr[t+1];
    }
    A2[(size_t)m * KENC + c] = f16bits(acc);
}

// ---------------- pack weights fp32 -> f16 single ---------------------------
__global__ void pack_b2s_k(const float* __restrict__ W, u16* __restrict__ B2,
                           int L, int N, int Npad, int Kreal, int K) {
    int idx = blockIdx.x * blockDim.x + threadIdx.x;
    if (idx >= L * Npad * K) return;
    int k = idx % K;
    int n = (idx / K) % Npad;
    int l = idx / (K * Npad);
    u16 hi = 0;
    if (n < N && k < Kreal)
        hi = f16bits(W[((size_t)l * N + n) * Kreal + k]);
    B2[((size_t)l * Npad + n) * K + k] = hi;
}

// ---------------- MFMA f16 GEMM: 64x128 tile, f16 output (in_proj) ----------
__global__ __launch_bounds__(256) void gemm_m64n128h(const u16* __restrict__ A2,
                                                     const u16* __restrict__ B2,
                                                     u16* __restrict__ C,
                                                     int K2, int ldc, int Nreal,
                                                     int nbx) {
    __shared__ u16 As[64 * 64];
    __shared__ u16 Bs[128 * 64];
    int nwg = gridDim.x;
    int lin = blockIdx.x;
    int q = nwg >> 3, r = nwg & 7;
    int xcd = lin & 7, idx = lin >> 3;
    int wg = ((xcd < r) ? xcd * (q + 1) : r * (q + 1) + (xcd - r) * q) + idx;
    int bx = wg % nbx, by = wg / nbx;

    int tid = threadIdx.x;
    int lane = tid & 63;
    int wave = tid >> 6;
    int wr = wave >> 1;
    int wc = wave & 1;
    int bm = by * 64;
    int bn = bx * 128;

    f32x4 acc[2][4] = {};
    const size_t ldA = (size_t)K2 * 2;

    for (int k0 = 0; k0 < K2; k0 += 64) {
        #pragma unroll
        for (int c = 0; c < 2; ++c) {
            int o = c * 4096 + tid * 16;
            int row = o >> 7;
            int slot = (o >> 4) & 7;
            int ss = slot ^ (row & 7);
            const char* src = (const char*)A2 + (size_t)(bm + row) * ldA
                              + (size_t)k0 * 2 + ss * 16;
            __builtin_amdgcn_global_load_lds(
                (const __attribute__((address_space(1))) u32*)src,
                (__attribute__((address_space(3))) u32*)((char*)As + o),
                16, 0, 0);
        }
        #pragma unroll
        for (int c = 0; c < 4; ++c) {
            int o = c * 4096 + tid * 16;
            int row = o >> 7;
            int slot = (o >> 4) & 7;
            int ss = slot ^ (row & 7);
            const char* src = (const char*)B2 + (size_t)(bn + row) * ldA
                              + (size_t)k0 * 2 + ss * 16;
            __builtin_amdgcn_global_load_lds(
                (const __attribute__((address_space(1))) u32*)src,
                (__attribute__((address_space(3))) u32*)((char*)Bs + o),
                16, 0, 0);
        }
        __syncthreads();
        #pragma unroll
        for (int kk = 0; kk < 2; ++kk) {
            int lslot = kk * 4 + (lane >> 4);
            half8 afr[2], bfr[4];
            #pragma unroll
            for (int n = 0; n < 4; ++n) {
                int row = wc * 64 + n * 16 + (lane & 15);
                int ps = lslot ^ (row & 7);
                bfr[n] = *(const half8*)((const char*)Bs + row * 128 + ps * 16);
            }
            #pragma unroll
            for (int m = 0; m < 2; ++m) {
                int row = wr * 32 + m * 16 + (lane & 15);
                int ps = lslot ^ (row & 7);
                afr[m] = *(const half8*)((const char*)As + row * 128 + ps * 16);
            }
            #pragma unroll
            for (int m = 0; m < 2; ++m)
                #pragma unroll
                for (int n = 0; n < 4; ++n)
                    acc[m][n] = __builtin_amdgcn_mfma_f32_16x16x32_f16(
                        bfr[n], afr[m], acc[m][n], 0, 0, 0);
        }
        __syncthreads();
    }

    int crow0 = bm + wr * 32;
    int ccol0 = bn + wc * 64;
    #pragma unroll
    for (int m = 0; m < 2; ++m) {
        int row = crow0 + m * 16 + (lane & 15);
        #pragma unroll
        for (int n = 0; n < 4; ++n) {
            int col = ccol0 + n * 16 + (lane >> 4) * 4;
            if (col < Nreal) {
                short4v hv;
                #pragma unroll
                for (int j = 0; j < 4; ++j) hv[j] = (short)f16bits(acc[m][n][j]);
                *(short4v*)(C + (size_t)row * ldc + col) = hv;
            }
        }
    }
}

// ---------------- MFMA f16 GEMM: 64x64 tile, f32 out (encoder) --------------
__global__ __launch_bounds__(256) void gemm_m64n64(const u16* __restrict__ A2,
                                                   const u16* __restrict__ B2,
                                                   float* __restrict__ C,
                                                   int K2, int ldc, int Nreal,
                                                   int nbx) {
    __shared__ u16 As[64 * 64];
    __shared__ u16 Bs[64 * 64];
    int nwg = gridDim.x;
    int lin = blockIdx.x;
    int q = nwg >> 3, r = nwg & 7;
    int xcd = lin & 7, idx = lin >> 3;
    int wg = ((xcd < r) ? xcd * (q + 1) : r * (q + 1) + (xcd - r) * q) + idx;
    int bx = wg % nbx, by = wg / nbx;

    int tid = threadIdx.x;
    int lane = tid & 63;
    int wave = tid >> 6;
    int wr = wave >> 1;
    int wc = wave & 1;
    int bm = by * 64;
    int bn = bx * 64;

    f32x4 acc[2][2] = {};
    const size_t ldA = (size_t)K2 * 2;

    for (int k0 = 0; k0 < K2; k0 += 64) {
        #pragma unroll
        for (int c = 0; c < 2; ++c) {
            int o = c * 4096 + tid * 16;
            int row = o >> 7;
            int slot = (o >> 4) & 7;
            int ss = slot ^ (row & 7);
            const char* src = (const char*)A2 + (size_t)(bm + row) * ldA
                              + (size_t)k0 * 2 + ss * 16;
            __builtin_amdgcn_global_load_lds(
                (const __attribute__((address_space(1))) u32*)src,
                (__attribute__((address_space(3))) u32*)((char*)As + o),
                16, 0, 0);
        }
        #pragma unroll
        for (int c = 0; c < 2; ++c) {
            int o = c * 4096 + tid * 16;
            int row = o >> 7;
            int slot = (o >> 4) & 7;
            int ss = slot ^ (row & 7);
            const char* src = (const char*)B2 + (size_t)(bn + row) * ldA
                              + (size_t)k0 * 2 + ss * 16;
            __builtin_amdgcn_global_load_lds(
                (const __attribute__((address_space(1))) u32*)src,
                (__attribute__((address_space(3))) u32*)((char*)Bs + o),
                16, 0, 0);
        }
        __syncthreads();
        #pragma unroll
        for (int kk = 0; kk < 2; ++kk) {
            int lslot = kk * 4 + (lane >> 4);
            half8 afr[2], bfr[2];
            #pragma unroll
            for (int n = 0; n < 2; ++n) {
                int row = wc * 32 + n * 16 + (lane & 15);
                int ps = lslot ^ (row & 7);
                bfr[n] = *(const half8*)((const char*)Bs + row * 128 + ps * 16);
            }
            #pragma unroll
            for (int m = 0; m < 2; ++m) {
                int row = wr * 32 + m * 16 + (lane & 15);
                int ps = lslot ^ (row & 7);
                afr[m] = *(const half8*)((const char*)As + row * 128 + ps * 16);
            }
            #pragma unroll
            for (int m = 0; m < 2; ++m)
                #pragma unroll
                for (int n = 0; n < 2; ++n)
                    acc[m][n] = __builtin_amdgcn_mfma_f32_16x16x32_f16(
                        bfr[n], afr[m], acc[m][n], 0, 0, 0);
        }
        __syncthreads();
    }

    int crow0 = bm + wr * 32;
    int ccol0 = bn + wc * 32;
    #pragma unroll
    for (int m = 0; m < 2; ++m) {
        int row = crow0 + m * 16 + (lane & 15);
        #pragma unroll
        for (int n = 0; n < 2; ++n) {
            int col = ccol0 + n * 16 + (lane >> 4) * 4;
            if (col < Nreal)
                *(f32x4*)(C + (size_t)row * ldc + col) = acc[m][n];
        }
    }
}

// ---------------- MFMA f16 GEMM: 64x64 tile, f16 out (out_proj) -------------
__global__ __launch_bounds__(256) void gemm_m64n64h(const u16* __restrict__ A2,
                                                    const u16* __restrict__ B2,
                                                    u16* __restrict__ C,
                                                    int K2, int ldc, int Nreal,
                                                    int nbx) {
    __shared__ u16 As[64 * 64];
    __shared__ u16 Bs[64 * 64];
    int nwg = gridDim.x;
    int lin = blockIdx.x;
    int q = nwg >> 3, r = nwg & 7;
    int xcd = lin & 7, idx = lin >> 3;
    int wg = ((xcd < r) ? xcd * (q + 1) : r * (q + 1) + (xcd - r) * q) + idx;
    int bx = wg % nbx, by = wg / nbx;

    int tid = threadIdx.x;
    int lane = tid & 63;
    int wave = tid >> 6;
    int wr = wave >> 1;
    int wc = wave & 1;
    int bm = by * 64;
    int bn = bx * 64;

    f32x4 acc[2][2] = {};
    const size_t ldA = (size_t)K2 * 2;

    for (int k0 = 0; k0 < K2; k0 += 64) {
        #pragma unroll
        for (int c = 0; c < 2; ++c) {
            int o = c * 4096 + tid * 16;
            int row = o >> 7;
            int slot = (o >> 4) & 7;
            int ss = slot ^ (row & 7);
            const char* src = (const char*)A2 + (size_t)(bm + row) * ldA
                              + (size_t)k0 * 2 + ss * 16;
            __builtin_amdgcn_global_load_lds(
                (const __attribute__((address_space(1))) u32*)src,
                (__attribute__((address_space(3))) u32*)((char*)As + o),
                16, 0, 0);
        }
        #pragma unroll
        for (int c = 0; c < 2; ++c) {
            int o = c * 4096 + tid * 16;
            int row = o >> 7;
            int slot = (o >> 4) & 7;
            int ss = slot ^ (row & 7);
            const char* src = (const char*)B2 + (size_t)(bn + row) * ldA
                              + (size_t)k0 * 2 + ss * 16;
            __builtin_amdgcn_global_load_lds(
                (const __attribute__((address_space(1))) u32*)src,
                (__attribute__((address_space(3))) u32*)((char*)Bs + o),
                16, 0, 0);
        }
        __syncthreads();
        #pragma unroll
        for (int kk = 0; kk < 2; ++kk) {
            int lslot = kk * 4 + (lane >> 4);
            half8 afr[2], bfr[2];
            #pragma unroll
            for (int n = 0; n < 2; ++n) {
                int row = wc * 32 + n * 16 + (lane & 15);
                int ps = lslot ^ (row & 7);
                bfr[n] = *(const half8*)((const char*)Bs + row * 128 + ps * 16);
            }
            #pragma unroll
            for (int m = 0; m < 2; ++m) {
                int row = wr * 32 + m * 16 + (lane & 15);
                int ps = lslot ^ (row & 7);
                afr[m] = *(const half8*)((const char*)As + row * 128 + ps * 16);
            }
            #pragma unroll
            for (int m = 0; m < 2; ++m)
                #pragma unroll
                for (int n = 0; n < 2; ++n)
                    acc[m][n] = __builtin_amdgcn_mfma_f32_16x16x32_f16(
                        bfr[n], afr[m], acc[m][n], 0, 0, 0);
        }
        __syncthreads();
    }

    int crow0 = bm + wr * 32;
    int ccol0 = bn + wc * 32;
    #pragma unroll
    for (int m = 0; m < 2; ++m) {
        int row = crow0 + m * 16 + (lane & 15);
        #pragma unroll
        for (int n = 0; n < 2; ++n) {
            int col = ccol0 + n * 16 + (lane >> 4) * 4;
            if (col < Nreal) {
                short4v hv;
                #pragma unroll
                for (int j = 0; j < 4; ++j) hv[j] = (short)f16bits(acc[m][n][j]);
                *(short4v*)(C + (size_t)row * ldc + col) = hv;
            }
        }
    }
}

// ---------------- encoder LN: h += mb+em; LN; write h + A2 (single, K=256) --
__global__ __launch_bounds__(256) void enc_ln_k(float* __restrict__ h,
        const float* __restrict__ mb, const float* __restrict__ em,
        const float* __restrict__ w, const float* __restrict__ bb,
        u16* __restrict__ A2) {
    int row = blockIdx.x * 4 + (threadIdx.x >> 6);
    int lane = threadIdx.x & 63;
    int e = lane * 4;
    float* hr = h + (size_t)row * DM;
    f32x4 v = *(const f32x4*)(hr + e);
    f32x4 vm = *(const f32x4*)(mb + e);
    f32x4 ve = *(const f32x4*)(em + e);
    float s = 0.f, sq = 0.f;
    #pragma unroll
    for (int j = 0; j < 4; ++j) {
        v[j] += vm[j] + ve[j];
        s += v[j];
        sq += v[j] * v[j];
    }
    s = wave_sum(s); sq = wave_sum(sq);
    float mean = s * (1.f / DM);
    float var = sq * (1.f / DM) - mean * mean;
    float r = rsqrtf(var + 1e-5f);
    f32x4 vw = *(const f32x4*)(w + e);
    f32x4 vb = *(const f32x4*)(bb + e);
    f32x4 o;
    short4v hi4;
    #pragma unroll
    for (int j = 0; j < 4; ++j) {
        float ov = (v[j] - mean) * r * vw[j] + vb[j];
        o[j] = ov;
        hi4[j] = (short)f16bits(ov);
    }
    *(f32x4*)(hr + e) = o;
    *(short4v*)(A2 + (size_t)row * 256 + e) = hi4;
}

// ---------------- B/C conv+silu + dt/dA (48 ch/row), zx f16 -----------------
__global__ void bc_dt_k(const u16* __restrict__ zx, const float* __restrict__ cw,
                        const float* __restrict__ cb, const float* __restrict__ dtb_in,
                        const float* __restrict__ A_log,
                        float* __restrict__ xbcs, float* __restrict__ dtdA) {
    int idx = blockIdx.x * blockDim.x + threadIdx.x;
    if (idx >= M_TOT * NBC) return;
    int c = idx % NBC;
    int m = idx / NBC;
    if (c < 32) {
        int cc = 512 + c;           // conv channel (B:512..527, C:528..543)
        int t = m % T_;
        float acc = cb[cc];
        #pragma unroll
        for (int k = 0; k < 4; ++k) {
            int tt = t - 3 + k;
            if (tt >= 0)
                acc += cw[cc*4+k] * f16tof(zx[(size_t)(m - (3 - k)) * DIP + DI + cc]);
        }
        xbcs[(size_t)m * NBC + c] = acc / (1.f + expf(-acc));
    } else {
        int h = c - 32;
        float xv = f16tof(zx[(size_t)m * DIP + DI + CD + h]) + dtb_in[h];
        float dt = (xv > 20.f) ? xv : log1pf(expf(xv));
        float A = -expf(A_log[h]);
        f32x2 dd; dd[0] = dt; dd[1] = expf(dt * A);
        *(f32x2*)(dtdA + (size_t)(m * NH + h) * 2) = dd;
    }
}

// ---------------- scan pass 1: chunk-local scan, conv(xh) in-register -------
__global__ __launch_bounds__(128) void scan1_k(const u16* __restrict__ zx,
        const float* __restrict__ xbcs, const float* __restrict__ dtdA,
        const float* __restrict__ cw, const float* __restrict__ cb,
        const float* __restrict__ D_skip,
        u16* __restrict__ y, float* __restrict__ S, float* __restrict__ Pprod) {
    int c   = blockIdx.x % NCHUNK;
    int bhq = blockIdx.x / NCHUNK;
    int b   = bhq >> 2;
    int hq  = bhq & 3;
    int h   = hq * 4 + (threadIdx.x >> 5);
    int p   = threadIdx.x & 31;
    int ch  = h * HD + p;          // x-channel 0..511
    float Dh = D_skip[h];
    float w0 = cw[ch*4+0], w1 = cw[ch*4+1], w2 = cw[ch*4+2], w3 = cw[ch*4+3];
    float cbb = cb[ch];
    float s[16];
    #pragma unroll
    for (int n = 0; n < 16; ++n) s[n] = 0.f;
    float pr = 1.f;
    int t0 = c * CLEN;
    int base = b * T_ + t0;
    const u16* xsrc = zx + (size_t)base * DIP + DI + ch;
    float xm3 = (t0 >= 3) ? f16tof(xsrc[-3 * (ptrdiff_t)DIP]) : 0.f;
    float xm2 = (t0 >= 2) ? f16tof(xsrc[-2 * (ptrdiff_t)DIP]) : 0.f;
    float xm1 = (t0 >= 1) ? f16tof(xsrc[-1 * (ptrdiff_t)DIP]) : 0.f;
    float x0  = f16tof(xsrc[0]);
    f32x2 dd = *(const f32x2*)(dtdA + (size_t)(base * NH + h) * 2);
    float dt = dd[0], dA = dd[1];
    const float* bcr = xbcs + (size_t)base * NBC;
    f32x4 Bv[4], Cv[4];
    #pragma unroll
    for (int qq = 0; qq < 4; ++qq) {
        Bv[qq] = *(const f32x4*)(bcr + qq * 4);
        Cv[qq] = *(const f32x4*)(bcr + 16 + qq * 4);
    }
    for (int t = 0; t < CLEN; ++t) {
        int m = base + t;
        int tn = (t + 1 < CLEN) ? t + 1 : t;
        float x0n = f16tof(xsrc[(size_t)tn * DIP]);
        f32x2 ddn = *(const f32x2*)(dtdA + (size_t)((base + tn) * NH + h) * 2);
        const float* bcn = xbcs + (size_t)(base + tn) * NBC;
        f32x4 Bn_[4], Cn_[4];
        #pragma unroll
        for (int qq = 0; qq < 4; ++qq) {
            Bn_[qq] = *(const f32x4*)(bcn + qq * 4);
            Cn_[qq] = *(const f32x4*)(bcn + 16 + qq * 4);
        }
        float a = cbb + w0 * xm3 + w1 * xm2 + w2 * xm1 + w3 * x0;
        float xh = a / (1.f + expf(-a));
        pr *= dA;
        float dtx = dt * xh;
        float ya0 = 0.f, ya1 = 0.f, ya2 = 0.f, ya3 = 0.f;
        #pragma unroll
        for (int qq = 0; qq < 4; ++qq) {
            #pragma unroll
            for (int j = 0; j < 4; ++j) {
                int n = qq * 4 + j;
                s[n] = fmaf(dA, s[n], dtx * Bv[qq][j]);
                float prod = s[n] * Cv[qq][j];
                if (qq == 0) ya0 += prod;
                else if (qq == 1) ya1 += prod;
                else if (qq == 2) ya2 += prod;
                else ya3 += prod;
            }
        }
        y[(size_t)m * DI + ch] = f16bits(fmaf(Dh, xh, (ya0 + ya1) + (ya2 + ya3)));
        xm3 = xm2; xm2 = xm1; xm1 = x0; x0 = x0n;
        dt = ddn[0]; dA = ddn[1];
        #pragma unroll
        for (int qq = 0; qq < 4; ++qq) { Bv[qq] = Bn_[qq]; Cv[qq] = Cn_[qq]; }
    }
    size_t sidx = ((((size_t)b * NH + h) * NCHUNK + c) * 32 + p) * 16;
    #pragma unroll
    for (int qq = 0; qq < 4; ++qq) {
        f32x4 v; v[0]=s[qq*4]; v[1]=s[qq*4+1]; v[2]=s[qq*4+2]; v[3]=s[qq*4+3];
        *(f32x4*)(S + sidx + qq * 4) = v;
    }
    if (p == 0) Pprod[(b * NH + h) * NCHUNK + c] = pr;
}

// ---------------- scan pass 3: s_init computed in-block; y += cum*(C.si) ----
__global__ __launch_bounds__(128) void scan3_k(const float* __restrict__ xbcs,
        const float* __restrict__ dtdA, const float* __restrict__ S,
        const float* __restrict__ Pprod, u16* __restrict__ y) {
    int c   = (blockIdx.x % (NCHUNK - 1)) + 1;
    int bhq = blockIdx.x / (NCHUNK - 1);
    int b   = bhq >> 2;
    int hq  = bhq & 3;
    int h   = hq * 4 + (threadIdx.x >> 5);
    int p   = threadIdx.x & 31;
    size_t bh = (size_t)b * NH + h;
    float si[16];
    #pragma unroll
    for (int n = 0; n < 16; ++n) si[n] = 0.f;
    float wgt = 1.f;
    for (int j = c - 1; j >= 0; --j) {
        size_t eidx = ((bh * NCHUNK + j) * 32 + p) * 16;
        #pragma unroll
        for (int qq = 0; qq < 4; ++qq) {
            f32x4 e = *(const f32x4*)(S + eidx + qq * 4);
            #pragma unroll
            for (int jj = 0; jj < 4; ++jj)
                si[qq*4+jj] = fmaf(wgt, e[jj], si[qq*4+jj]);
        }
        wgt *= Pprod[bh * NCHUNK + j];
    }
    float cum = 1.f;
    int base = b * T_ + c * CLEN;
    for (int t = 0; t < CLEN; ++t) {
        int m = base + t;
        f32x2 dd = *(const f32x2*)(dtdA + (size_t)(m * NH + h) * 2);
        cum *= dd[1];
        const float* Cr = xbcs + (size_t)m * NBC + 16;
        float dot = 0.f;
        #pragma unroll
        for (int qq = 0; qq < 4; ++qq) {
            f32x4 Cv = *(const f32x4*)(Cr + qq * 4);
            #pragma unroll
            for (int jj = 0; jj < 4; ++jj) dot = fmaf(si[qq*4+jj], Cv[jj], dot);
        }
        size_t yi = (size_t)m * DI + h * HD + p;
        y[yi] = f16bits(f16tof(y[yi]) + cum * dot);
    }
}

// ---------------- gated RMSNorm -> A2 single-f16 (y,z f16) ------------------
__global__ __launch_bounds__(256) void gate_rms_k(const u16* __restrict__ y,
        const u16* __restrict__ zx, const float* __restrict__ nw,
        u16* __restrict__ A2) {
    int row = blockIdx.x * 4 + (threadIdx.x >> 6);
    int lane = threadIdx.x & 63;
    int e0 = lane * 4, e1 = 256 + lane * 4;
    const u16* yr = y + (size_t)row * DI;
    const u16* zr = zx + (size_t)row * DIP;
    short4v yh0 = *(const short4v*)(yr + e0);
    short4v yh1 = *(const short4v*)(yr + e1);
    short4v zh0 = *(const short4v*)(zr + e0);
    short4v zh1 = *(const short4v*)(zr + e1);
    f32x4 g0, g1;
    float sq = 0.f;
    #pragma unroll
    for (int j = 0; j < 4; ++j) {
        float z0 = f16tof((u16)zh0[j]);
        float z1 = f16tof((u16)zh1[j]);
        g0[j] = f16tof((u16)yh0[j]) * (z0 / (1.f + expf(-z0)));
        g1[j] = f16tof((u16)yh1[j]) * (z1 / (1.f + expf(-z1)));
        sq += g0[j] * g0[j] + g1[j] * g1[j];
    }
    sq = wave_sum(sq);
    float r = rsqrtf(sq * (1.f / DI) + 1e-5f);
    f32x4 w0 = *(const f32x4*)(nw + e0);
    f32x4 w1 = *(const f32x4*)(nw + e1);
    u16* ar = A2 + (size_t)row * 512;
    short4v hi4;
    #pragma unroll
    for (int j = 0; j < 4; ++j)
        hi4[j] = (short)f16bits(g0[j] * r * w0[j]);
    *(short4v*)(ar + e0) = hi4;
    #pragma unroll
    for (int j = 0; j < 4; ++j)
        hi4[j] = (short)f16bits(g1[j] * r * w1[j]);
    *(short4v*)(ar + e1) = hi4;
}

// ---------------- h = LN(c + h), c in f16 -> h + A2 (single, K=256) ---------
__global__ __launch_bounds__(256) void add_ln_k(float* __restrict__ h,
        const u16* __restrict__ c, const float* __restrict__ w,
        const float* __restrict__ bb, u16* __restrict__ A2) {
    int row = blockIdx.x * 4 + (threadIdx.x >> 6);
    int lane = threadIdx.x & 63;
    int e = lane * 4;
    float* hr = h + (size_t)row * DM;
    const u16* cr = c + (size_t)row * DM;
    f32x4 v = *(const f32x4*)(hr + e);
    short4v ch4 = *(const short4v*)(cr + e);
    float s = 0.f, sq = 0.f;
    #pragma unroll
    for (int j = 0; j < 4; ++j) {
        v[j] += f16tof((u16)ch4[j]);
        s += v[j];
        sq += v[j] * v[j];
    }
    s = wave_sum(s); sq = wave_sum(sq);
    float mean = s * (1.f / DM);
    float var = sq * (1.f / DM) - mean * mean;
    float r = rsqrtf(var + 1e-5f);
    f32x4 vw = *(const f32x4*)(w + e);
    f32x4 vb = *(const f32x4*)(bb + e);
    f32x4 o;
    short4v hi4;
    #pragma unroll
    for (int j = 0; j < 4; ++j) {
        float ov = (v[j] - mean) * r * vw[j] + vb[j];
        o[j] = ov;
        hi4[j] = (short)f16bits(ov);
    }
    *(f32x4*)(hr + e) = o;
    *(short4v*)(A2 + (size_t)row * 256 + e) = hi4;
}

// ---------------- fused mean-pool + head ------------------------------------
__global__ __launch_bounds__(256) void pool_head_k(const float* __restrict__ h,
        const float* __restrict__ w1, const float* __restrict__ b1,
        const float* __restrict__ w2, const float* __restrict__ b2,
        float* __restrict__ out) {
    __shared__ float pl[DM];
    __shared__ float red[2];
    int b = blockIdx.x, tid = threadIdx.x;
    float s = 0.f;
    for (int t = 0; t < T_; ++t) s += h[(size_t)(b * T_ + t) * DM + tid];
    pl[tid] = s * (1.f / T_);
    __syncthreads();
    float v = 0.f;
    if (tid < 128) {
        float acc = b1[tid];
        #pragma unroll 4
        for (int d = 0; d < DM; ++d) acc = fmaf(pl[d], w1[tid * DM + d], acc);
        v = fmaxf(acc, 0.f) * w2[tid];
    }
    #pragma unroll
    for (int off = 32; off > 0; off >>= 1) v += __shfl_xor(v, off);
    if (tid == 0) red[0] = v;
    if (tid == 64) red[1] = v;
    __syncthreads();
    if (tid == 0) out[b] = red[0] + red[1] + b2[0];
}

extern "C" void kernel_launch(void* const* d_in, const int* in_sizes, int n_in,
                              void* d_out, int out_size, void* d_ws, size_t ws_size,
                              hipStream_t stream) {
    const float* x         = (const float*)d_in[0];
    const float* emb       = (const float*)d_in[1];
    const float* sconv_w   = (const float*)d_in[2];
    const float* sconv_b   = (const float*)d_in[3];
    const float* mixer_w   = (const float*)d_in[4];
    const float* mixer_b   = (const float*)d_in[5];
    const float* enc_ln_w  = (const float*)d_in[6];
    const float* enc_ln_b  = (const float*)d_in[7];
    const float* in_proj_w = (const float*)d_in[8];
    const float* conv_w    = (const float*)d_in[9];
    const float* conv_b    = (const float*)d_in[10];
    const float* dt_bias   = (const float*)d_in[11];
    const float* A_log     = (const float*)d_in[12];
    const float* D_skip    = (const float*)d_in[13];
    const float* norm_w    = (const float*)d_in[14];
    const float* out_proj_w= (const float*)d_in[15];
    const float* ln_w      = (const float*)d_in[16];
    const float* ln_b      = (const float*)d_in[17];
    const float* head1_w   = (const float*)d_in[18];
    const float* head1_b   = (const float*)d_in[19];
    const float* head2_w   = (const float*)d_in[20];
    const float* head2_b   = (const float*)d_in[21];
    float* out = (float*)d_out;

    float* ws  = (float*)d_ws;
    float* h    = ws;                          // M*DM f32
    float* xbcs = h    + (size_t)M_TOT * DM;   // M*48 f32
    float* dtdA = xbcs + (size_t)M_TOT * NBC;  // M*NH*2 f32
    float* em   = dtdA + (size_t)M_TOT * NH*2; // 256
    float* S    = em + 256;                    // B*NH*NCHUNK*512 f32
    float* Pprod = S + (size_t)B_*NH*NCHUNK*512;  // 10240
    u16* zx   = (u16*)(Pprod + 10240);         // M*DIP f16
    u16* y16  = zx + (size_t)M_TOT * DIP;      // M*DI f16
    u16* cbuf = y16 + (size_t)M_TOT * DI;      // M*DM f16
    u16* A2   = cbuf + (size_t)M_TOT * DM;     // M*512 f16
    u16* B2e  = A2 + (size_t)M_TOT * 512;      // 256*192
    u16* B2i  = B2e + (size_t)256 * 192;       // 4*1152*256
    u16* B2o  = B2i + (size_t)4 * 1152 * 256;  // 4*256*512

    // ---- one-time packs ----
    emb_mean_k<<<1, DM, 0, stream>>>(emb, em);
    pack_b2s_k<<<(256 * KENC + 255) / 256, 256, 0, stream>>>(
        mixer_w, B2e, 1, DM, DM, NCH_, KENC);
    pack_b2s_k<<<(4 * 1152 * DM + 255) / 256, 256, 0, stream>>>(
        in_proj_w, B2i, 4, DIP, 1152, DM, DM);
    pack_b2s_k<<<(4 * 256 * DI + 255) / 256, 256, 0, stream>>>(
        out_proj_w, B2o, 4, DM, DM, DI, DI);

    // ---- encoder ----
    xsA2_k<<<(M_TOT * KENC + 255) / 256, 256, 0, stream>>>(x, sconv_w, sconv_b, A2);
    gemm_m64n64<<<4 * 200, 256, 0, stream>>>(A2, B2e, h, KENC, DM, DM, 4);
    enc_ln_k<<<M_TOT / 4, 256, 0, stream>>>(h, mixer_b, em, enc_ln_w, enc_ln_b, A2);

    for (int l = 0; l < 4; ++l) {
        // in_proj: single-f16, K2=256, N=1072 (pad 1152), f16 output
        gemm_m64n128h<<<9 * 200, 256, 0, stream>>>(
            A2, B2i + (size_t)l * 1152 * 256, zx, 256, DIP, DIP, 9);

        bc_dt_k<<<(M_TOT * NBC + 255) / 256, 256, 0, stream>>>(
            zx, conv_w + l * CD * 4, conv_b + l * CD, dt_bias + l * NH,
            A_log + l * NH, xbcs, dtdA);

        scan1_k<<<B_ * 4 * NCHUNK, 128, 0, stream>>>(
            zx, xbcs, dtdA, conv_w + l * CD * 4, conv_b + l * CD,
            D_skip + l * NH, y16, S, Pprod);
        scan3_k<<<B_ * 4 * (NCHUNK - 1), 128, 0, stream>>>(xbcs, dtdA, S, Pprod, y16);

        gate_rms_k<<<M_TOT / 4, 256, 0, stream>>>(y16, zx, norm_w + l * DI, A2);

        // out_proj: single-f16, K2=512, N=256, f16 output
        gemm_m64n64h<<<4 * 200, 256, 0, stream>>>(
            A2, B2o + (size_t)l * 256 * 512, cbuf, 512, DM, DM, 4);

        add_ln_k<<<M_TOT / 4, 256, 0, stream>>>(h, cbuf, ln_w + l * DM, ln_b + l * DM, A2);
    }

    pool_head_k<<<B_, 256, 0, stream>>>(h, head1_w, head1_b, head2_w, head2_b, out);
}